// Round 7
// baseline (491.532 us; speedup 1.0000x reference)
//
#include <hip/hip_runtime.h>
#include <hip/hip_bf16.h>

typedef __hip_bfloat16 bf16;

#define F 18
#define P 128
#define H 256
#define HEADS 8
#define HD 32
#define NCLS 625
#define FPH (F*P*H)        // 589824
#define RPS 589824         // one scale's per-frame-row buffer: 2304 rows x 256

// ---- fp32 workspace layout (float slots) ----
#define OF_FLAG   0
#define OF_PTN    16
#define OF_RT     48
#define OF_W      80
#define OF_OSUM   128
#define OF_CTX    512
#define OF_FW     (OF_CTX + FPH)      // 590336
#define WO2_HALTW 0
#define WO2_HALTB 256
#define WO2_CLSB  272
#define WO2_CLSW  912
#define WO2_BQ    160912
#define WO2_BK    161680
#define WO2_BV    162448
#define WO2_BO    163216
#define FW_TOTAL  163984
#define NF_TOTAL  (OF_FW + FW_TOTAL)  // 754320 floats ~= 3.0 MB

// ---- bf16 workspace layout (bf16 slots after fp32 area) ----
#define BB_WQT 0
#define BB_WKT 196608
#define BB_WVT 393216
#define BB_WOT 589824
#define BB_INP 786432                  // FPH
#define BB_QB  1376256                 // 3*RPS
#define BB_KB  (BB_QB + 3*RPS)         // 3145728
#define BB_VT  (BB_KB + 3*RPS)         // 4915200  V transposed: [scale][256][2304]
#define BB_AO  (BB_VT + 3*RPS)         // 6684672  summed attn out: [scale][2304][256]
#define BB_OB  (BB_AO + 3*RPS)         // 8454144  per-window attn out: 22016 x 256
#define OB_ROWS0 0
#define OB_ROWS1 4352
#define OB_ROWS2 12032
// total ws ~= 3.0 MB fp32 + 28.2 MB bf16 ~= 31.2 MB

typedef __attribute__((ext_vector_type(8))) short s8v;
typedef __attribute__((ext_vector_type(4))) short s4v;
typedef __attribute__((ext_vector_type(4))) float f4v;

__device__ __forceinline__ float b2f(bf16 x){ return __bfloat162float(x); }
__device__ __forceinline__ unsigned short f2bu(float x){
    union { __hip_bfloat16 h; unsigned short u; } cv; cv.h = __float2bfloat16(x); return cv.u;
}
__device__ __forceinline__ float bu2f(unsigned short u){
    union { unsigned int x; float f; } cv; cv.x = ((unsigned int)u) << 16; return cv.f;
}
__device__ __forceinline__ void b2x2(unsigned int u, float& a, float& b){
    union { unsigned int x; float f; } c1, c2;
    c1.x = u << 16; c2.x = u & 0xffff0000u; a = c1.f; b = c2.f;
}
__device__ __forceinline__ unsigned int pk2(float a, float b){
    return (unsigned int)f2bu(a) | ((unsigned int)f2bu(b) << 16);
}
__device__ __forceinline__ int imin(int a,int b){ return a<b?a:b; }
__device__ __forceinline__ int imax(int a,int b){ return a>b?a:b; }

// ---------------------------------------------------------------------------
// dtype probe: bf16 vs fp32 input buffers
// ---------------------------------------------------------------------------
__global__ __launch_bounds__(256) void k_detect(const unsigned int* __restrict__ embw,
                                                float* __restrict__ ws)
{
    __shared__ int cnt;
    if (threadIdx.x == 0) cnt = 0;
    __syncthreads();
    int c = 0;
    for (int i = threadIdx.x; i < 512; i += 256){
        unsigned int e = (embw[i] >> 7) & 0xffu;
        if (e >= 120u && e <= 130u) c++;
    }
    atomicAdd(&cnt, c);
    __syncthreads();
    if (threadIdx.x == 0) ws[OF_FLAG] = (cnt > 256) ? 1.f : 0.f;
}

// ---------------------------------------------------------------------------
// convert: mode 0 fp32 copy; mode 1 bf16 transposed weight (3x256x256);
// mode 2 embed -> bf16 mirror only
// ---------------------------------------------------------------------------
struct ConvArgs {
    const void* src[13];
    int mode[13];
    int n[13];
    int off[13];
};
__global__ __launch_bounds__(256) void k_convert(ConvArgs a, float* __restrict__ ws,
                                                 bf16* __restrict__ bb)
{
    int gid = blockIdx.x*256 + threadIdx.x;
    const int isbf = (ws[OF_FLAG] != 0.f);
#pragma unroll
    for (int t = 0; t < 13; ++t){
        if (gid < a.n[t]){
            float v = isbf ? b2f(((const bf16*)a.src[t])[gid])
                           : ((const float*)a.src[t])[gid];
            if (a.mode[t] == 0){
                ws[a.off[t] + gid] = v;
            } else if (a.mode[t] == 1){
                const int i = gid >> 16, rem = gid & 65535;
                const int k = rem >> 8, nn = rem & 255;
                bb[a.off[t] + (i << 16) + (nn << 8) + k] = __float2bfloat16(v);
            } else {
                bb[BB_INP + gid] = __float2bfloat16(v);
            }
            return;
        }
        gid -= a.n[t];
    }
}

// ---------------------------------------------------------------------------
// halting probability + ACT state update (one block per frame), bf16 inputs
// ---------------------------------------------------------------------------
__global__ __launch_bounds__(128) void k_halt(const bf16* __restrict__ inpb,
        const float* __restrict__ hW, const float* __restrict__ hB,
        float* __restrict__ ws)
{
    __shared__ float hw[H];
    __shared__ float red[128];
    const int f = blockIdx.x, t = threadIdx.x;
    hw[t] = hW[t]; hw[t+128] = hW[t+128];
    __syncthreads();
    const uint4* row = (const uint4*)(inpb + (size_t)(f*P + t)*H);
    float acc = hB[0];
#pragma unroll
    for (int i = 0; i < 16; ++i){
        const uint4 u = row[i];
        float a0,a1,a2,a3,a4,a5,a6,a7;
        b2x2(u.x,a0,a1); b2x2(u.y,a2,a3); b2x2(u.z,a4,a5); b2x2(u.w,a6,a7);
        const int b = i*16;
        acc = fmaf(a0,hw[b+0],acc); acc = fmaf(a1,hw[b+1],acc);
        acc = fmaf(a2,hw[b+2],acc); acc = fmaf(a3,hw[b+3],acc);
        acc = fmaf(a4,hw[b+4],acc); acc = fmaf(a5,hw[b+5],acc);
        acc = fmaf(a6,hw[b+6],acc); acc = fmaf(a7,hw[b+7],acc);
    }
    red[t] = 1.f/(1.f + __expf(-acc));
    __syncthreads();
    for (int s = 64; s > 0; s >>= 1){ if (t < s) red[t] += red[t+s]; __syncthreads(); }
    if (t == 0){
        float pf = red[0] * (1.f/P);
        float pt = ws[OF_PTN + f], rt = ws[OF_RT + f];
        float run  = (pt < 1.f) ? 1.f : 0.f;
        float cond = (pt + pf*run > 0.99f) ? 1.f : 0.f;
        float nh   = cond*run;
        run = (1.f - cond)*run;
        pt += pf*run;
        rt += nh*(1.f - pt);
        pt += nh*rt;
        ws[OF_PTN + f] = pt; ws[OF_RT + f] = rt;
        ws[OF_W   + f] = pf*run + nh*rt;
    }
}

// ---------------------------------------------------------------------------
// QKV projection, all 3 scales (blockIdx.z). Projects only the F*P=2304
// distinct frame rows. Q,K written row-major; V written TRANSPOSED
// (vT[dim][row], 8B packed stores) so attention needs no LDS transpose.
// ---------------------------------------------------------------------------
__global__ __launch_bounds__(256) void k_qkv_mfma(const bf16* __restrict__ X,
        const bf16* __restrict__ WQT, const bf16* __restrict__ WKT,
        const bf16* __restrict__ WVT, const float* __restrict__ fw,
        bf16* __restrict__ qball, bf16* __restrict__ kball, bf16* __restrict__ vTall)
{
    const int tid = threadIdx.x;
    const int wave = tid >> 6, lane = tid & 63;
    const int lq = lane & 15, quad = lane >> 4;
    const int m0 = blockIdx.x * 64;
    const int n0 = blockIdx.y * 64 + wave * 16;
    const int i  = blockIdx.z;
    const int wo = i << 16;

    const bf16* arow[4];
#pragma unroll
    for (int mt = 0; mt < 4; ++mt)
        arow[mt] = X + (size_t)(m0 + mt*16 + lq)*H + quad*8;
    const bf16* bqp = WQT + wo + (size_t)(n0 + lq)*H + quad*8;
    const bf16* bkp = WKT + wo + (size_t)(n0 + lq)*H + quad*8;
    const bf16* bvp = WVT + wo + (size_t)(n0 + lq)*H + quad*8;

    f4v aq[4], ak[4], av[4];
#pragma unroll
    for (int mt = 0; mt < 4; ++mt){
        aq[mt] = (f4v){0.f,0.f,0.f,0.f};
        ak[mt] = (f4v){0.f,0.f,0.f,0.f};
        av[mt] = (f4v){0.f,0.f,0.f,0.f};
    }
#pragma unroll
    for (int k0 = 0; k0 < H; k0 += 32){
        const s8v bfq = *(const s8v*)(bqp + k0);
        const s8v bfk = *(const s8v*)(bkp + k0);
        const s8v bfv = *(const s8v*)(bvp + k0);
#pragma unroll
        for (int mt = 0; mt < 4; ++mt){
            const s8v af = *(const s8v*)(arow[mt] + k0);
            aq[mt] = __builtin_amdgcn_mfma_f32_16x16x32_bf16(af, bfq, aq[mt], 0, 0, 0);
            ak[mt] = __builtin_amdgcn_mfma_f32_16x16x32_bf16(af, bfk, ak[mt], 0, 0, 0);
            av[mt] = __builtin_amdgcn_mfma_f32_16x16x32_bf16(af, bfv, av[mt], 0, 0, 0);
        }
    }
    bf16* qo = qball + (size_t)i*RPS;
    bf16* ko = kball + (size_t)i*RPS;
    bf16* vT = vTall + (size_t)i*RPS;
    const float bqv = fw[WO2_BQ + i*256 + n0 + lq];
    const float bkv = fw[WO2_BK + i*256 + n0 + lq];
    const float bvv = fw[WO2_BV + i*256 + n0 + lq];
#pragma unroll
    for (int mt = 0; mt < 4; ++mt){
#pragma unroll
        for (int r = 0; r < 4; ++r){
            const size_t row = (size_t)(m0 + mt*16 + quad*4 + r)*H + n0 + lq;
            qo[row] = __float2bfloat16(aq[mt][r] + bqv);
            ko[row] = __float2bfloat16(ak[mt][r] + bkv);
        }
        // vT: rows m0+mt*16+quad*4 .. +3 are consecutive -> one 8B store
        uint2 vst;
        vst.x = pk2(av[mt][0] + bvv, av[mt][1] + bvv);
        vst.y = pk2(av[mt][2] + bvv, av[mt][3] + bvv);
        *(uint2*)(vT + (size_t)(n0 + lq)*2304 + m0 + mt*16 + quad*4) = vst;
    }
}

// ---------------------------------------------------------------------------
// Flash attention, all scales, LDS-free & atomic-free. Per-128k-chunk
// softmax. V^T fragments load directly from the pre-transposed global vT.
// Epilogue writes O/(l*cnt) bf16 into the per-window token buffer obuf.
// ---------------------------------------------------------------------------
#if __has_builtin(__builtin_amdgcn_mfma_f32_16x16x16bf16_1k)
#define ATTN_HAVE_1K 1
#else
#define ATTN_HAVE_1K 0
#endif

__global__ __launch_bounds__(256) void k_attn_fused(const bf16* __restrict__ qball,
        const bf16* __restrict__ kball, const bf16* __restrict__ vTall,
        bf16* __restrict__ obuf)
{
    const int bid = blockIdx.x;
    int i, rel, s, nw, nqt, obase;
    if (bid < 544)       { i = 0; rel = bid;        s = 2; nw = 17; nqt = 4;  obase = OB_ROWS0; }
    else if (bid < 1504) { i = 1; rel = bid - 544;  s = 4; nw = 15; nqt = 8;  obase = OB_ROWS1; }
    else                 { i = 2; rel = bid - 1504; s = 6; nw = 13; nqt = 12; obase = OB_ROWS2; }
    const int nch = s;                   // chunks of 128 k-rows
    const int S = nqt << 6;
    const int qt = rel % nqt;
    const int rest = rel / nqt;
    const int h = rest & 7;
    const int w = rest >> 3;

    const bf16* qs = qball + (size_t)i*RPS;
    const bf16* ks = kball + (size_t)i*RPS;
    const bf16* vTs = vTall + (size_t)i*RPS;

    const int tid = threadIdx.x;
    const int wave = tid >> 6, lane = tid & 63;
    const int lq = lane & 15, quad = lane >> 4;
    const int row0 = w*P;
    const int qrow = row0 + qt*64 + wave*16 + lq;    // global frame row

    // Q B-frag, pre-scaled by 1/sqrt(32)
    s8v qf;
    {
        const float SC = 0.17677669529663687f;
        const bf16* qptr = qs + (size_t)qrow*H + h*HD + quad*8;
        union { s8v v; unsigned short u[8]; } qin, qsc;
        qin.v = *(const s8v*)qptr;
#pragma unroll
        for (int j = 0; j < 8; ++j) qsc.u[j] = f2bu(bu2f(qin.u[j]) * SC);
        qf = qsc.v;
    }

    // V^T row pointers for this lane's two output dims (lq, lq+16)
    const bf16* vr0 = vTs + (size_t)(h*HD + lq)*2304;
    const bf16* vr1 = vTs + (size_t)(h*HD + 16 + lq)*2304;

    float m = -3e38f, l = 0.f;
    f4v o0 = {0.f,0.f,0.f,0.f}, o1 = {0.f,0.f,0.f,0.f};

    for (int ch = 0; ch < nch; ++ch){
        const int kbase = row0 + ch*128;
        // 8 independent QK^T MFMAs -> 32 scores/lane (S^T layout: q = lq)
        f4v st[8];
#pragma unroll
        for (int tt = 0; tt < 4; ++tt){
            const bf16* kp0 = ks + (size_t)(kbase + tt*32 + lq)*H + h*HD + quad*8;
            const s8v kf0 = *(const s8v*)kp0;
            const s8v kf1 = *(const s8v*)(kp0 + 16*H);
            f4v z = {0.f,0.f,0.f,0.f};
            st[2*tt]   = __builtin_amdgcn_mfma_f32_16x16x32_bf16(kf0, qf, z, 0, 0, 0);
            st[2*tt+1] = __builtin_amdgcn_mfma_f32_16x16x32_bf16(kf1, qf, z, 0, 0, 0);
        }
        // one softmax update per 128-k chunk
        float mc = -3e38f;
#pragma unroll
        for (int t8 = 0; t8 < 8; ++t8)
            mc = fmaxf(mc, fmaxf(fmaxf(st[t8][0], st[t8][1]), fmaxf(st[t8][2], st[t8][3])));
        mc = fmaxf(mc, __shfl_xor(mc, 16));
        mc = fmaxf(mc, __shfl_xor(mc, 32));
        const float mn = fmaxf(m, mc);
        const float alpha = __expf(m - mn);
        float ls = 0.f;
#pragma unroll
        for (int t8 = 0; t8 < 8; ++t8){
#pragma unroll
            for (int r = 0; r < 4; ++r){
                const float e = __expf(st[t8][r] - mn);
                st[t8][r] = e;
                ls += e;
            }
        }
        ls += __shfl_xor(ls, 16);
        ls += __shfl_xor(ls, 32);
        l = l*alpha + ls;
        m = mn;
        o0 = o0 * alpha;
        o1 = o1 * alpha;

        // PV: P frags direct from C-layout; V^T frags direct from global
#pragma unroll
        for (int tt = 0; tt < 4; ++tt){
            const int kq = kbase + tt*32;
#if ATTN_HAVE_1K
            union { unsigned int u[2]; s4v v; } pf0, pf1;
            pf0.u[0] = pk2(st[2*tt][0],   st[2*tt][1]);
            pf0.u[1] = pk2(st[2*tt][2],   st[2*tt][3]);
            pf1.u[0] = pk2(st[2*tt+1][0], st[2*tt+1][1]);
            pf1.u[1] = pk2(st[2*tt+1][2], st[2*tt+1][3]);
            const s4v va00 = *(const s4v*)(vr0 + kq      + (quad<<2));
            const s4v va01 = *(const s4v*)(vr0 + kq + 16 + (quad<<2));
            const s4v va10 = *(const s4v*)(vr1 + kq      + (quad<<2));
            const s4v va11 = *(const s4v*)(vr1 + kq + 16 + (quad<<2));
            o0 = __builtin_amdgcn_mfma_f32_16x16x16bf16_1k(va00, pf0.v, o0, 0, 0, 0);
            o0 = __builtin_amdgcn_mfma_f32_16x16x16bf16_1k(va01, pf1.v, o0, 0, 0, 0);
            o1 = __builtin_amdgcn_mfma_f32_16x16x16bf16_1k(va10, pf0.v, o1, 0, 0, 0);
            o1 = __builtin_amdgcn_mfma_f32_16x16x16bf16_1k(va11, pf1.v, o1, 0, 0, 0);
#else
            const unsigned int p0x = pk2(st[2*tt][0],   st[2*tt][1]);
            const unsigned int p0y = pk2(st[2*tt][2],   st[2*tt][3]);
            const unsigned int p1x = pk2(st[2*tt+1][0], st[2*tt+1][1]);
            const unsigned int p1y = pk2(st[2*tt+1][2], st[2*tt+1][3]);
            const int srcA = lq + ((( quad<<1)      & 3) << 4);
            const int srcB = lq + ((((quad<<1) | 1) & 3) << 4);
            const unsigned int a0 = (unsigned int)__shfl((int)p0x, srcA);
            const unsigned int a1 = (unsigned int)__shfl((int)p0y, srcA);
            const unsigned int a2 = (unsigned int)__shfl((int)p0x, srcB);
            const unsigned int a3 = (unsigned int)__shfl((int)p0y, srcB);
            const unsigned int b0 = (unsigned int)__shfl((int)p1x, srcA);
            const unsigned int b1 = (unsigned int)__shfl((int)p1y, srcA);
            const unsigned int b2 = (unsigned int)__shfl((int)p1x, srcB);
            const unsigned int b3 = (unsigned int)__shfl((int)p1y, srcB);
            const bool hi = (quad >= 2);
            union { unsigned int u[4]; s8v v; } bfr;
            bfr.u[0] = hi ? b0 : a0; bfr.u[1] = hi ? b1 : a1;
            bfr.u[2] = hi ? b2 : a2; bfr.u[3] = hi ? b3 : a3;
            const s8v va0 = *(const s8v*)(vr0 + kq + (quad<<3));
            const s8v va1 = *(const s8v*)(vr1 + kq + (quad<<3));
            o0 = __builtin_amdgcn_mfma_f32_16x16x32_bf16(va0, bfr.v, o0, 0, 0, 0);
            o1 = __builtin_amdgcn_mfma_f32_16x16x32_bf16(va1, bfr.v, o1, 0, 0, 0);
#endif
        }
    }
    // epilogue: lane holds O^T[d=quad*4+r (+16)][q=lq]; write O/(l*cnt)
    const int fframe = qrow >> 7;
    const int cnt = imin(nw-1, fframe) - imax(0, fframe - s + 1) + 1;
    const float scl = 1.f / (l * (float)cnt);
    bf16* op = obuf + (size_t)(obase + w*S + qt*64 + wave*16 + lq)*H + h*HD;
    *(unsigned int*)(op + quad*4)          = pk2(o0[0]*scl, o0[1]*scl);
    *(unsigned int*)(op + quad*4 + 2)      = pk2(o0[2]*scl, o0[3]*scl);
    *(unsigned int*)(op + 16 + quad*4)     = pk2(o1[0]*scl, o1[1]*scl);
    *(unsigned int*)(op + 16 + quad*4 + 2) = pk2(o1[2]*scl, o1[3]*scl);
}

// ---------------------------------------------------------------------------
// overlap-add gather: ao_s[frame row] = sum over contributing windows of obuf
// (already scaled by 1/(l*cnt) in attention). Deterministic, atomic-free.
// ---------------------------------------------------------------------------
__global__ __launch_bounds__(256) void k_oadd(const bf16* __restrict__ obuf,
                                              bf16* __restrict__ aoall)
{
    const int r = blockIdx.x, i = blockIdx.y, c = threadIdx.x;
    int s, nw, obase;
    if (i == 0)      { s = 2; nw = 17; obase = OB_ROWS0; }
    else if (i == 1) { s = 4; nw = 15; obase = OB_ROWS1; }
    else             { s = 6; nw = 13; obase = OB_ROWS2; }
    const int S = s << 7;
    const int f = r >> 7, p = r & 127;
    const int wlo = imax(0, f - s + 1), whi = imin(nw - 1, f);
    float sum = 0.f;
    for (int w = wlo; w <= whi; ++w)
        sum += b2f(obuf[(size_t)(obase + w*S + (f - w)*P + p)*H + c]);
    aoall[(size_t)i*RPS + (size_t)r*H + c] = __float2bfloat16(sum);
}

// ---------------------------------------------------------------------------
// Output projection over the frame grid, 3 scales accumulated in one MFMA
// accumulator, fused with the transition epilogue. A-frags direct from bf16 ao.
// ---------------------------------------------------------------------------
__global__ __launch_bounds__(256) void k_oproj_trans(const bf16* __restrict__ aoall,
        const bf16* __restrict__ WOT, const float* __restrict__ ws,
        bf16* __restrict__ inpb, float* __restrict__ context)
{
    const int tid = threadIdx.x;
    const int wave = tid >> 6, lane = tid & 63;
    const int lq = lane & 15, quad = lane >> 4;
    const int m0 = blockIdx.x * 64;
    const int n0 = blockIdx.y * 64 + wave * 16;

    f4v acc[4];
#pragma unroll
    for (int mt = 0; mt < 4; ++mt) acc[mt] = (f4v){0.f,0.f,0.f,0.f};

    for (int i = 0; i < 3; ++i){
        const bf16* A = aoall + (size_t)i*RPS;
        const bf16* bp = WOT + (i<<16) + (size_t)(n0 + lq)*H + quad*8;
#pragma unroll
        for (int k0 = 0; k0 < H; k0 += 32){
            const s8v bf_ = *(const s8v*)(bp + k0);
#pragma unroll
            for (int mt = 0; mt < 4; ++mt){
                const s8v af = *(const s8v*)(A + (size_t)(m0 + mt*16 + lq)*H + k0 + quad*8);
                acc[mt] = __builtin_amdgcn_mfma_f32_16x16x32_bf16(af, bf_, acc[mt], 0, 0, 0);
            }
        }
    }
    const int col = n0 + lq;
    const float bosum = ws[OF_FW + WO2_BO + col] + ws[OF_FW + WO2_BO + 256 + col]
                      + ws[OF_FW + WO2_BO + 512 + col];
#pragma unroll
    for (int mt = 0; mt < 4; ++mt){
#pragma unroll
        for (int r = 0; r < 4; ++r){
            const int row = m0 + mt*16 + quad*4 + r;
            const float tval = 0.25f * (acc[mt][r] + bosum);
            const float wf = ws[OF_W + (row >> 7)];
            const size_t idx = (size_t)row*H + col;
            inpb[idx] = __float2bfloat16(tval);
            context[idx] = tval*wf + context[idx]*(1.f - wf);
        }
    }
}

// ---------------------------------------------------------------------------
// reduce context over all rows -> osum[256]
// ---------------------------------------------------------------------------
__global__ __launch_bounds__(256) void k_reduce(const float* __restrict__ context,
        float* __restrict__ osum)
{
    const int hcol = threadIdx.x;
    const float* base = context + (size_t)blockIdx.x * 64 * H;
    float s = 0.f;
#pragma unroll 8
    for (int r = 0; r < 64; ++r) s += base[(size_t)r*H + hcol];
    atomicAdd(&osum[hcol], s);
}

// ---------------------------------------------------------------------------
// classes = osum @ cls_W + cls_b
// ---------------------------------------------------------------------------
__global__ __launch_bounds__(256) void k_classes(const float* __restrict__ ws,
        void* __restrict__ out)
{
    __shared__ float os[H];
    const int tid = threadIdx.x;
    os[tid] = ws[OF_OSUM + tid];
    __syncthreads();
    const int n = blockIdx.x*256 + tid;
    if (n < NCLS){
        const float* clsW = ws + OF_FW + WO2_CLSW;
        float acc = ws[OF_FW + WO2_CLSB + n];
        for (int hh = 0; hh < H; ++hh) acc = fmaf(os[hh], clsW[(size_t)hh*NCLS + n], acc);
        if (ws[OF_FLAG] != 0.f) ((bf16*)out)[n] = __float2bfloat16(acc);
        else                    ((float*)out)[n] = acc;
    }
}

// ---------------------------------------------------------------------------
extern "C" void kernel_launch(void* const* d_in, const int* in_sizes, int n_in,
                              void* d_out, int out_size, void* d_ws, size_t ws_size,
                              hipStream_t stream)
{
    (void)in_sizes; (void)n_in; (void)out_size; (void)ws_size;
    float* WS = (float*)d_ws;
    float* context = WS + OF_CTX;
    float* fw      = WS + OF_FW;
    bf16*  bb      = (bf16*)(WS + NF_TOTAL);
    bf16*  inpb    = bb + BB_INP;
    bf16*  qb      = bb + BB_QB;
    bf16*  kb      = bb + BB_KB;
    bf16*  vT      = bb + BB_VT;
    bf16*  ao      = bb + BB_AO;
    bf16*  ob      = bb + BB_OB;

    (void)hipMemsetAsync(WS, 0, (size_t)OF_FW*4, stream);   // state + context
    k_detect<<<1, 256, 0, stream>>>((const unsigned int*)d_in[0], WS);

    ConvArgs ca;
    const int srcs[13]  = {0, 3, 4, 8, 9, 11, 13, 15, 17, 10, 12, 14, 16};
    const int modes[13] = {2, 0, 0, 0, 0, 0, 0, 0, 0, 1, 1, 1, 1};
    const int ns[13]    = {FPH, 256, 1, H*NCLS, NCLS, 768, 768, 768, 768,
                           196608, 196608, 196608, 196608};
    const int offs[13]  = {0,
        OF_FW+WO2_HALTW, OF_FW+WO2_HALTB, OF_FW+WO2_CLSW, OF_FW+WO2_CLSB,
        OF_FW+WO2_BQ, OF_FW+WO2_BK, OF_FW+WO2_BV, OF_FW+WO2_BO,
        BB_WQT, BB_WKT, BB_WVT, BB_WOT};
    int total = 0;
    for (int t = 0; t < 13; ++t){
        ca.src[t] = d_in[srcs[t]]; ca.mode[t] = modes[t];
        ca.n[t] = ns[t]; ca.off[t] = offs[t]; total += ns[t];
    }
    k_convert<<<(total + 255)/256, 256, 0, stream>>>(ca, WS, bb);

    for (int it = 0; it < 2; ++it){
        k_halt<<<F, 128, 0, stream>>>(inpb, fw + WO2_HALTW, fw + WO2_HALTB, WS);
        k_qkv_mfma<<<dim3(36, 4, 3), 256, 0, stream>>>(inpb,
            bb+BB_WQT, bb+BB_WKT, bb+BB_WVT, fw, qb, kb, vT);
        k_attn_fused<<<2752, 256, 0, stream>>>(qb, kb, vT, ob);
        k_oadd<<<dim3(2304, 3), 256, 0, stream>>>(ob, ao);
        k_oproj_trans<<<dim3(36, 4), 256, 0, stream>>>(ao, bb+BB_WOT, WS,
            inpb, context);
    }
    k_reduce<<<36, 256, 0, stream>>>(context, WS + OF_OSUM);
    k_classes<<<3, 256, 0, stream>>>(WS, d_out);
}

// Round 8
// 298.907 us; speedup vs baseline: 1.6444x; 1.6444x over previous
//
#include <hip/hip_runtime.h>
#include <hip/hip_bf16.h>

typedef __hip_bfloat16 bf16;

#define F 18
#define P 128
#define H 256
#define HEADS 8
#define HD 32
#define NCLS 625
#define FPH (F*P*H)        // 589824
#define RPS 589824         // per-scale buffer: 2304 rows x 256 (any permutation)
#define NT16 144           // 2304/16 row tiles per scale

// ---- fp32 workspace layout (float slots) ----
#define OF_FLAG   0
#define OF_PTN    16
#define OF_RT     48
#define OF_W      80
#define OF_OSUM   128
#define OF_CTX    512
#define OF_FW     (OF_CTX + FPH)      // 590336
#define WO2_HALTW 0
#define WO2_HALTB 256
#define WO2_CLSB  272
#define WO2_CLSW  912
#define WO2_BQ    160912
#define WO2_BK    161680
#define WO2_BV    162448
#define WO2_BO    163216
#define FW_TOTAL  163984
#define NF_TOTAL  (OF_FW + FW_TOTAL)  // 754320 floats ~= 3.0 MB

// ---- bf16 workspace layout (bf16 slots after fp32 area) ----
#define BB_WQT 0
#define BB_WKT 196608
#define BB_WVT 393216
#define BB_WOT 589824
#define BB_INP 786432                  // FPH
#define BB_QB  1376256                 // 3*RPS (swizzled frag layout)
#define BB_KB  (BB_QB + 3*RPS)
#define BB_VT  (BB_KB + 3*RPS)
#define BB_AO  (BB_VT + 3*RPS)         // summed attn out, row-major
#define BB_OB  (BB_AO + 3*RPS)         // per-window attn out: 22016 x 256
#define OB_ROWS0 0
#define OB_ROWS1 4352
#define OB_ROWS2 12032

typedef __attribute__((ext_vector_type(8))) short s8v;
typedef __attribute__((ext_vector_type(4))) short s4v;
typedef __attribute__((ext_vector_type(4))) float f4v;

__device__ __forceinline__ float b2f(bf16 x){ return __bfloat162float(x); }
__device__ __forceinline__ unsigned short f2bu(float x){
    union { __hip_bfloat16 h; unsigned short u; } cv; cv.h = __float2bfloat16(x); return cv.u;
}
__device__ __forceinline__ float bu2f(unsigned short u){
    union { unsigned int x; float f; } cv; cv.x = ((unsigned int)u) << 16; return cv.f;
}
__device__ __forceinline__ void b2x2(unsigned int u, float& a, float& b){
    union { unsigned int x; float f; } c1, c2;
    c1.x = u << 16; c2.x = u & 0xffff0000u; a = c1.f; b = c2.f;
}
__device__ __forceinline__ unsigned int pk2(float a, float b){
    return (unsigned int)f2bu(a) | ((unsigned int)f2bu(b) << 16);
}
__device__ __forceinline__ int imin(int a,int b){ return a<b?a:b; }
__device__ __forceinline__ int imax(int a,int b){ return a>b?a:b; }

// ---------------------------------------------------------------------------
// dtype probe: bf16 vs fp32 input buffers
// ---------------------------------------------------------------------------
__global__ __launch_bounds__(256) void k_detect(const unsigned int* __restrict__ embw,
                                                float* __restrict__ ws)
{
    __shared__ int cnt;
    if (threadIdx.x == 0) cnt = 0;
    __syncthreads();
    int c = 0;
    for (int i = threadIdx.x; i < 512; i += 256){
        unsigned int e = (embw[i] >> 7) & 0xffu;
        if (e >= 120u && e <= 130u) c++;
    }
    atomicAdd(&cnt, c);
    __syncthreads();
    if (threadIdx.x == 0) ws[OF_FLAG] = (cnt > 256) ? 1.f : 0.f;
}

// ---------------------------------------------------------------------------
// convert: mode 0 fp32 copy; mode 1 bf16 transposed weight (3x256x256);
// mode 2 embed -> bf16 mirror only
// ---------------------------------------------------------------------------
struct ConvArgs {
    const void* src[13];
    int mode[13];
    int n[13];
    int off[13];
};
__global__ __launch_bounds__(256) void k_convert(ConvArgs a, float* __restrict__ ws,
                                                 bf16* __restrict__ bb)
{
    int gid = blockIdx.x*256 + threadIdx.x;
    const int isbf = (ws[OF_FLAG] != 0.f);
#pragma unroll
    for (int t = 0; t < 13; ++t){
        if (gid < a.n[t]){
            float v = isbf ? b2f(((const bf16*)a.src[t])[gid])
                           : ((const float*)a.src[t])[gid];
            if (a.mode[t] == 0){
                ws[a.off[t] + gid] = v;
            } else if (a.mode[t] == 1){
                const int i = gid >> 16, rem = gid & 65535;
                const int k = rem >> 8, nn = rem & 255;
                bb[a.off[t] + (i << 16) + (nn << 8) + k] = __float2bfloat16(v);
            } else {
                bb[BB_INP + gid] = __float2bfloat16(v);
            }
            return;
        }
        gid -= a.n[t];
    }
}

// ---------------------------------------------------------------------------
// halting probability + ACT state update (one block per frame), bf16 inputs
// ---------------------------------------------------------------------------
__global__ __launch_bounds__(128) void k_halt(const bf16* __restrict__ inpb,
        const float* __restrict__ hW, const float* __restrict__ hB,
        float* __restrict__ ws)
{
    __shared__ float hw[H];
    __shared__ float red[128];
    const int f = blockIdx.x, t = threadIdx.x;
    hw[t] = hW[t]; hw[t+128] = hW[t+128];
    __syncthreads();
    const uint4* row = (const uint4*)(inpb + (size_t)(f*P + t)*H);
    float acc = hB[0];
#pragma unroll
    for (int i = 0; i < 16; ++i){
        const uint4 u = row[i];
        float a0,a1,a2,a3,a4,a5,a6,a7;
        b2x2(u.x,a0,a1); b2x2(u.y,a2,a3); b2x2(u.z,a4,a5); b2x2(u.w,a6,a7);
        const int b = i*16;
        acc = fmaf(a0,hw[b+0],acc); acc = fmaf(a1,hw[b+1],acc);
        acc = fmaf(a2,hw[b+2],acc); acc = fmaf(a3,hw[b+3],acc);
        acc = fmaf(a4,hw[b+4],acc); acc = fmaf(a5,hw[b+5],acc);
        acc = fmaf(a6,hw[b+6],acc); acc = fmaf(a7,hw[b+7],acc);
    }
    red[t] = 1.f/(1.f + __expf(-acc));
    __syncthreads();
    for (int s = 64; s > 0; s >>= 1){ if (t < s) red[t] += red[t+s]; __syncthreads(); }
    if (t == 0){
        float pf = red[0] * (1.f/P);
        float pt = ws[OF_PTN + f], rt = ws[OF_RT + f];
        float run  = (pt < 1.f) ? 1.f : 0.f;
        float cond = (pt + pf*run > 0.99f) ? 1.f : 0.f;
        float nh   = cond*run;
        run = (1.f - cond)*run;
        pt += pf*run;
        rt += nh*(1.f - pt);
        pt += nh*rt;
        ws[OF_PTN + f] = pt; ws[OF_RT + f] = rt;
        ws[OF_W   + f] = pf*run + nh*rt;
    }
}

// ---------------------------------------------------------------------------
// QKV projection, 3 scales (blockIdx.z), 2304 frame rows. Outputs stored in
// MFMA-FRAGMENT-SWIZZLED layouts so attention loads are 100% coalesced:
//   Q/K: idx(h,t16,lane,j) = ((h*144+t16)*64 + lane)*8 + j
//        holds X[t16*16 + (lane&15)][h*32 + (lane>>4)*8 + j]
//   V  : idx(h,k16,lane,half,r) = ((h*144+k16)*64 + lane)*8 + half*4 + r
//        holds V[k16*16 + ((lane>>4)<<2) + r][h*32 + half*16 + (lane&15)]
// ---------------------------------------------------------------------------
__global__ __launch_bounds__(256) void k_qkv_mfma(const bf16* __restrict__ X,
        const bf16* __restrict__ WQT, const bf16* __restrict__ WKT,
        const bf16* __restrict__ WVT, const float* __restrict__ fw,
        bf16* __restrict__ qball, bf16* __restrict__ kball, bf16* __restrict__ vball)
{
    const int tid = threadIdx.x;
    const int wave = tid >> 6, lane = tid & 63;
    const int lq = lane & 15, quad = lane >> 4;
    const int m0 = blockIdx.x * 64;
    const int n0 = blockIdx.y * 64 + wave * 16;
    const int i  = blockIdx.z;
    const int wo = i << 16;

    const bf16* arow[4];
#pragma unroll
    for (int mt = 0; mt < 4; ++mt)
        arow[mt] = X + (size_t)(m0 + mt*16 + lq)*H + quad*8;
    const bf16* bqp = WQT + wo + (size_t)(n0 + lq)*H + quad*8;
    const bf16* bkp = WKT + wo + (size_t)(n0 + lq)*H + quad*8;
    const bf16* bvp = WVT + wo + (size_t)(n0 + lq)*H + quad*8;

    f4v aq[4], ak[4], av[4];
#pragma unroll
    for (int mt = 0; mt < 4; ++mt){
        aq[mt] = (f4v){0.f,0.f,0.f,0.f};
        ak[mt] = (f4v){0.f,0.f,0.f,0.f};
        av[mt] = (f4v){0.f,0.f,0.f,0.f};
    }
#pragma unroll
    for (int k0 = 0; k0 < H; k0 += 32){
        const s8v bfq = *(const s8v*)(bqp + k0);
        const s8v bfk = *(const s8v*)(bkp + k0);
        const s8v bfv = *(const s8v*)(bvp + k0);
#pragma unroll
        for (int mt = 0; mt < 4; ++mt){
            const s8v af = *(const s8v*)(arow[mt] + k0);
            aq[mt] = __builtin_amdgcn_mfma_f32_16x16x32_bf16(af, bfq, aq[mt], 0, 0, 0);
            ak[mt] = __builtin_amdgcn_mfma_f32_16x16x32_bf16(af, bfk, ak[mt], 0, 0, 0);
            av[mt] = __builtin_amdgcn_mfma_f32_16x16x32_bf16(af, bfv, av[mt], 0, 0, 0);
        }
    }
    bf16* qo = qball + (size_t)i*RPS;
    bf16* ko = kball + (size_t)i*RPS;
    bf16* vo = vball + (size_t)i*RPS;
    const int col = n0 + lq;                    // output column 0..255
    const float bqv = fw[WO2_BQ + i*256 + col];
    const float bkv = fw[WO2_BK + i*256 + col];
    const float bvv = fw[WO2_BV + i*256 + col];
    const int h2 = col >> 5;                    // head
    const int q2 = (col >> 3) & 3;              // dim-quad for Q/K frag
    const int j2 = col & 7;                     // dim-elem for Q/K frag
    const int half = (col >> 4) & 1;            // dim-half for V frag
    const int lqv  = col & 15;                  // dim-lane for V frag
#pragma unroll
    for (int mt = 0; mt < 4; ++mt){
        const int t16 = (m0 >> 4) + mt;         // 16-row tile index
        const size_t qkbase = ((size_t)(h2*NT16 + t16)*64 + 16*q2 + quad*4)*8 + j2;
#pragma unroll
        for (int r = 0; r < 4; ++r){
            // lane2 = (quad*4+r) + 16*q2 ; row = t16*16 + quad*4 + r
            qo[qkbase + (size_t)r*8] = __float2bfloat16(aq[mt][r] + bqv);
            ko[qkbase + (size_t)r*8] = __float2bfloat16(ak[mt][r] + bkv);
        }
        // V: lane2 = lqv + 16*quad ; r consecutive -> one 8B store
        const size_t vbase = ((size_t)(h2*NT16 + t16)*64 + lqv + 16*quad)*8 + half*4;
        uint2 vst;
        vst.x = pk2(av[mt][0] + bvv, av[mt][1] + bvv);
        vst.y = pk2(av[mt][2] + bvv, av[mt][3] + bvv);
        *(uint2*)(vo + vbase) = vst;
    }
}

// ---------------------------------------------------------------------------
// Flash attention, all scales, LDS-free, atomic-free, ALL LOADS COALESCED
// (lane*16B from the swizzled Q/K/V layouts). Per-128k-chunk softmax.
// ---------------------------------------------------------------------------
#if __has_builtin(__builtin_amdgcn_mfma_f32_16x16x16bf16_1k)
#define ATTN_HAVE_1K 1
#else
#define ATTN_HAVE_1K 0
#endif

__global__ __launch_bounds__(256) void k_attn_fused(const bf16* __restrict__ qball,
        const bf16* __restrict__ kball, const bf16* __restrict__ vball,
        bf16* __restrict__ obuf)
{
    const int bid = blockIdx.x;
    int i, rel, s, nw, nqt, obase;
    if (bid < 544)       { i = 0; rel = bid;        s = 2; nw = 17; nqt = 4;  obase = OB_ROWS0; }
    else if (bid < 1504) { i = 1; rel = bid - 544;  s = 4; nw = 15; nqt = 8;  obase = OB_ROWS1; }
    else                 { i = 2; rel = bid - 1504; s = 6; nw = 13; nqt = 12; obase = OB_ROWS2; }
    const int nch = s;                   // chunks of 128 k-rows
    const int S = nqt << 6;
    const int qt = rel % nqt;
    const int rest = rel / nqt;
    const int h = rest & 7;
    const int w = rest >> 3;

    const bf16* qs = qball + (size_t)i*RPS;
    const bf16* ks = kball + (size_t)i*RPS;
    const bf16* vs = vball + (size_t)i*RPS;

    const int tid = threadIdx.x;
    const int wave = tid >> 6, lane = tid & 63;
    const int lq = lane & 15, quad = lane >> 4;

    // Q B-frag: coalesced lane*16B load from swizzled Q, pre-scaled 1/sqrt(32)
    const int qt16 = w*8 + qt*4 + wave;             // 16-row q tile
    s8v qf;
    {
        const float SC = 0.17677669529663687f;
        union { s8v v; unsigned short u[8]; } qin, qsc;
        qin.v = *(const s8v*)(qs + ((size_t)(h*NT16 + qt16)*64 + lane)*8);
#pragma unroll
        for (int j = 0; j < 8; ++j) qsc.u[j] = f2bu(bu2f(qin.u[j]) * SC);
        qf = qsc.v;
    }

    float m = -3e38f, l = 0.f;
    f4v o0 = {0.f,0.f,0.f,0.f}, o1 = {0.f,0.f,0.f,0.f};

    for (int ch = 0; ch < nch; ++ch){
        const int kt0 = w*8 + ch*8;                 // first 16-row k tile
        // 8 independent QK^T MFMAs, K frags coalesced
        f4v st[8];
#pragma unroll
        for (int tt = 0; tt < 4; ++tt){
            const s8v kf0 = *(const s8v*)(ks + ((size_t)(h*NT16 + kt0 + tt*2    )*64 + lane)*8);
            const s8v kf1 = *(const s8v*)(ks + ((size_t)(h*NT16 + kt0 + tt*2 + 1)*64 + lane)*8);
            f4v z = {0.f,0.f,0.f,0.f};
            st[2*tt]   = __builtin_amdgcn_mfma_f32_16x16x32_bf16(kf0, qf, z, 0, 0, 0);
            st[2*tt+1] = __builtin_amdgcn_mfma_f32_16x16x32_bf16(kf1, qf, z, 0, 0, 0);
        }
        // one softmax update per 128-k chunk
        float mc = -3e38f;
#pragma unroll
        for (int t8 = 0; t8 < 8; ++t8)
            mc = fmaxf(mc, fmaxf(fmaxf(st[t8][0], st[t8][1]), fmaxf(st[t8][2], st[t8][3])));
        mc = fmaxf(mc, __shfl_xor(mc, 16));
        mc = fmaxf(mc, __shfl_xor(mc, 32));
        const float mn = fmaxf(m, mc);
        const float alpha = __expf(m - mn);
        float ls = 0.f;
#pragma unroll
        for (int t8 = 0; t8 < 8; ++t8){
#pragma unroll
            for (int r = 0; r < 4; ++r){
                const float e = __expf(st[t8][r] - mn);
                st[t8][r] = e;
                ls += e;
            }
        }
        ls += __shfl_xor(ls, 16);
        ls += __shfl_xor(ls, 32);
        l = l*alpha + ls;
        m = mn;
        o0 = o0 * alpha;
        o1 = o1 * alpha;

        // PV: P frags direct from C-layout; V frags coalesced 16B loads
#pragma unroll
        for (int tt = 0; tt < 4; ++tt){
            // V tile a: k rows tt*32..+15 ; tile b: +16..+31
            union { uint4 q; s4v h2v[2]; } vA, vB;
            vA.q = *(const uint4*)(vs + ((size_t)(h*NT16 + kt0 + tt*2    )*64 + lane)*8);
            vB.q = *(const uint4*)(vs + ((size_t)(h*NT16 + kt0 + tt*2 + 1)*64 + lane)*8);
#if ATTN_HAVE_1K
            union { unsigned int u[2]; s4v v; } pf0, pf1;
            pf0.u[0] = pk2(st[2*tt][0],   st[2*tt][1]);
            pf0.u[1] = pk2(st[2*tt][2],   st[2*tt][3]);
            pf1.u[0] = pk2(st[2*tt+1][0], st[2*tt+1][1]);
            pf1.u[1] = pk2(st[2*tt+1][2], st[2*tt+1][3]);
            o0 = __builtin_amdgcn_mfma_f32_16x16x16bf16_1k(vA.h2v[0], pf0.v, o0, 0, 0, 0);
            o0 = __builtin_amdgcn_mfma_f32_16x16x16bf16_1k(vB.h2v[0], pf1.v, o0, 0, 0, 0);
            o1 = __builtin_amdgcn_mfma_f32_16x16x16bf16_1k(vA.h2v[1], pf0.v, o1, 0, 0, 0);
            o1 = __builtin_amdgcn_mfma_f32_16x16x16bf16_1k(vB.h2v[1], pf1.v, o1, 0, 0, 0);
#else
            // K=32 PV fallback: reformat P C-frags -> B-frag via 8 shuffles,
            // V A-frag (dims lq / lq+16, k = tt*32+quad*8+m) from two 16B
            // loads at lane2a/lane2b (qh=quad>>1 selects tile, ql=quad&1).
            const int qh = quad >> 1, ql = quad & 1;
            const int ktv = kt0 + tt*2 + qh;
            union { uint4 q; s4v h2v[2]; } wA, wB;
            wA.q = *(const uint4*)(vs + ((size_t)(h*NT16 + ktv)*64 + lq + 32*ql)*8);
            wB.q = *(const uint4*)(vs + ((size_t)(h*NT16 + ktv)*64 + lq + 32*ql + 16)*8);
            union { s4v h2v[2]; s8v v; } va0, va1;
            va0.h2v[0] = wA.h2v[0]; va0.h2v[1] = wB.h2v[0];
            va1.h2v[0] = wA.h2v[1]; va1.h2v[1] = wB.h2v[1];
            const unsigned int p0x = pk2(st[2*tt][0],   st[2*tt][1]);
            const unsigned int p0y = pk2(st[2*tt][2],   st[2*tt][3]);
            const unsigned int p1x = pk2(st[2*tt+1][0], st[2*tt+1][1]);
            const unsigned int p1y = pk2(st[2*tt+1][2], st[2*tt+1][3]);
            const int srcA = lq + ((( quad<<1)      & 3) << 4);
            const int srcB = lq + ((((quad<<1) | 1) & 3) << 4);
            const unsigned int a0 = (unsigned int)__shfl((int)p0x, srcA);
            const unsigned int a1 = (unsigned int)__shfl((int)p0y, srcA);
            const unsigned int a2 = (unsigned int)__shfl((int)p0x, srcB);
            const unsigned int a3 = (unsigned int)__shfl((int)p0y, srcB);
            const unsigned int b0 = (unsigned int)__shfl((int)p1x, srcA);
            const unsigned int b1 = (unsigned int)__shfl((int)p1y, srcA);
            const unsigned int b2 = (unsigned int)__shfl((int)p1x, srcB);
            const unsigned int b3 = (unsigned int)__shfl((int)p1y, srcB);
            const bool hi = (quad >= 2);
            union { unsigned int u[4]; s8v v; } bfr;
            bfr.u[0] = hi ? b0 : a0; bfr.u[1] = hi ? b1 : a1;
            bfr.u[2] = hi ? b2 : a2; bfr.u[3] = hi ? b3 : a3;
            o0 = __builtin_amdgcn_mfma_f32_16x16x32_bf16(va0.v, bfr.v, o0, 0, 0, 0);
            o1 = __builtin_amdgcn_mfma_f32_16x16x32_bf16(va1.v, bfr.v, o1, 0, 0, 0);
#endif
        }
    }
    // epilogue: lane holds O^T[d=quad*4+r (+16)][q=lq]; write O/(l*cnt)
    const int qrow = w*P + qt*64 + wave*16 + lq;
    const int fframe = qrow >> 7;
    const int cnt = imin(nw-1, fframe) - imax(0, fframe - s + 1) + 1;
    const float scl = 1.f / (l * (float)cnt);
    bf16* op = obuf + (size_t)(obase + w*S + qt*64 + wave*16 + lq)*H + h*HD;
    *(unsigned int*)(op + quad*4)          = pk2(o0[0]*scl, o0[1]*scl);
    *(unsigned int*)(op + quad*4 + 2)      = pk2(o0[2]*scl, o0[3]*scl);
    *(unsigned int*)(op + 16 + quad*4)     = pk2(o1[0]*scl, o1[1]*scl);
    *(unsigned int*)(op + 16 + quad*4 + 2) = pk2(o1[2]*scl, o1[3]*scl);
}

// ---------------------------------------------------------------------------
// overlap-add gather: ao_s[frame row] = sum over contributing windows of obuf
// ---------------------------------------------------------------------------
__global__ __launch_bounds__(256) void k_oadd(const bf16* __restrict__ obuf,
                                              bf16* __restrict__ aoall)
{
    const int r = blockIdx.x, i = blockIdx.y, c = threadIdx.x;
    int s, nw, obase;
    if (i == 0)      { s = 2; nw = 17; obase = OB_ROWS0; }
    else if (i == 1) { s = 4; nw = 15; obase = OB_ROWS1; }
    else             { s = 6; nw = 13; obase = OB_ROWS2; }
    const int S = s << 7;
    const int f = r >> 7, p = r & 127;
    const int wlo = imax(0, f - s + 1), whi = imin(nw - 1, f);
    float sum = 0.f;
    for (int w = wlo; w <= whi; ++w)
        sum += b2f(obuf[(size_t)(obase + w*S + (f - w)*P + p)*H + c]);
    aoall[(size_t)i*RPS + (size_t)r*H + c] = __float2bfloat16(sum);
}

// ---------------------------------------------------------------------------
// Output projection over the frame grid, 3 scales accumulated, fused with
// the transition epilogue. A-frags direct from bf16 ao (row-major).
// ---------------------------------------------------------------------------
__global__ __launch_bounds__(256) void k_oproj_trans(const bf16* __restrict__ aoall,
        const bf16* __restrict__ WOT, const float* __restrict__ ws,
        bf16* __restrict__ inpb, float* __restrict__ context)
{
    const int tid = threadIdx.x;
    const int wave = tid >> 6, lane = tid & 63;
    const int lq = lane & 15, quad = lane >> 4;
    const int m0 = blockIdx.x * 64;
    const int n0 = blockIdx.y * 64 + wave * 16;

    f4v acc[4];
#pragma unroll
    for (int mt = 0; mt < 4; ++mt) acc[mt] = (f4v){0.f,0.f,0.f,0.f};

    for (int i = 0; i < 3; ++i){
        const bf16* A = aoall + (size_t)i*RPS;
        const bf16* bp = WOT + (i<<16) + (size_t)(n0 + lq)*H + quad*8;
#pragma unroll
        for (int k0 = 0; k0 < H; k0 += 32){
            const s8v bf_ = *(const s8v*)(bp + k0);
#pragma unroll
            for (int mt = 0; mt < 4; ++mt){
                const s8v af = *(const s8v*)(A + (size_t)(m0 + mt*16 + lq)*H + k0 + quad*8);
                acc[mt] = __builtin_amdgcn_mfma_f32_16x16x32_bf16(af, bf_, acc[mt], 0, 0, 0);
            }
        }
    }
    const int col = n0 + lq;
    const float bosum = ws[OF_FW + WO2_BO + col] + ws[OF_FW + WO2_BO + 256 + col]
                      + ws[OF_FW + WO2_BO + 512 + col];
#pragma unroll
    for (int mt = 0; mt < 4; ++mt){
#pragma unroll
        for (int r = 0; r < 4; ++r){
            const int row = m0 + mt*16 + quad*4 + r;
            const float tval = 0.25f * (acc[mt][r] + bosum);
            const float wf = ws[OF_W + (row >> 7)];
            const size_t idx = (size_t)row*H + col;
            inpb[idx] = __float2bfloat16(tval);
            context[idx] = tval*wf + context[idx]*(1.f - wf);
        }
    }
}

// ---------------------------------------------------------------------------
// reduce context over all rows -> osum[256]
// ---------------------------------------------------------------------------
__global__ __launch_bounds__(256) void k_reduce(const float* __restrict__ context,
        float* __restrict__ osum)
{
    const int hcol = threadIdx.x;
    const float* base = context + (size_t)blockIdx.x * 64 * H;
    float s = 0.f;
#pragma unroll 8
    for (int r = 0; r < 64; ++r) s += base[(size_t)r*H + hcol];
    atomicAdd(&osum[hcol], s);
}

// ---------------------------------------------------------------------------
// classes = osum @ cls_W + cls_b
// ---------------------------------------------------------------------------
__global__ __launch_bounds__(256) void k_classes(const float* __restrict__ ws,
        void* __restrict__ out)
{
    __shared__ float os[H];
    const int tid = threadIdx.x;
    os[tid] = ws[OF_OSUM + tid];
    __syncthreads();
    const int n = blockIdx.x*256 + tid;
    if (n < NCLS){
        const float* clsW = ws + OF_FW + WO2_CLSW;
        float acc = ws[OF_FW + WO2_CLSB + n];
        for (int hh = 0; hh < H; ++hh) acc = fmaf(os[hh], clsW[(size_t)hh*NCLS + n], acc);
        if (ws[OF_FLAG] != 0.f) ((bf16*)out)[n] = __float2bfloat16(acc);
        else                    ((float*)out)[n] = acc;
    }
}

// ---------------------------------------------------------------------------
extern "C" void kernel_launch(void* const* d_in, const int* in_sizes, int n_in,
                              void* d_out, int out_size, void* d_ws, size_t ws_size,
                              hipStream_t stream)
{
    (void)in_sizes; (void)n_in; (void)out_size; (void)ws_size;
    float* WS = (float*)d_ws;
    float* context = WS + OF_CTX;
    float* fw      = WS + OF_FW;
    bf16*  bb      = (bf16*)(WS + NF_TOTAL);
    bf16*  inpb    = bb + BB_INP;
    bf16*  qb      = bb + BB_QB;
    bf16*  kb      = bb + BB_KB;
    bf16*  vT      = bb + BB_VT;
    bf16*  ao      = bb + BB_AO;
    bf16*  ob      = bb + BB_OB;

    (void)hipMemsetAsync(WS, 0, (size_t)OF_FW*4, stream);   // state + context
    k_detect<<<1, 256, 0, stream>>>((const unsigned int*)d_in[0], WS);

    ConvArgs ca;
    const int srcs[13]  = {0, 3, 4, 8, 9, 11, 13, 15, 17, 10, 12, 14, 16};
    const int modes[13] = {2, 0, 0, 0, 0, 0, 0, 0, 0, 1, 1, 1, 1};
    const int ns[13]    = {FPH, 256, 1, H*NCLS, NCLS, 768, 768, 768, 768,
                           196608, 196608, 196608, 196608};
    const int offs[13]  = {0,
        OF_FW+WO2_HALTW, OF_FW+WO2_HALTB, OF_FW+WO2_CLSW, OF_FW+WO2_CLSB,
        OF_FW+WO2_BQ, OF_FW+WO2_BK, OF_FW+WO2_BV, OF_FW+WO2_BO,
        BB_WQT, BB_WKT, BB_WVT, BB_WOT};
    int total = 0;
    for (int t = 0; t < 13; ++t){
        ca.src[t] = d_in[srcs[t]]; ca.mode[t] = modes[t];
        ca.n[t] = ns[t]; ca.off[t] = offs[t]; total += ns[t];
    }
    k_convert<<<(total + 255)/256, 256, 0, stream>>>(ca, WS, bb);

    for (int it = 0; it < 2; ++it){
        k_halt<<<F, 128, 0, stream>>>(inpb, fw + WO2_HALTW, fw + WO2_HALTB, WS);
        k_qkv_mfma<<<dim3(36, 4, 3), 256, 0, stream>>>(inpb,
            bb+BB_WQT, bb+BB_WKT, bb+BB_WVT, fw, qb, kb, vT);
        k_attn_fused<<<2752, 256, 0, stream>>>(qb, kb, vT, ob);
        k_oadd<<<dim3(2304, 3), 256, 0, stream>>>(ob, ao);
        k_oproj_trans<<<dim3(36, 4), 256, 0, stream>>>(ao, bb+BB_WOT, WS,
            inpb, context);
    }
    k_reduce<<<36, 256, 0, stream>>>(context, WS + OF_OSUM);
    k_classes<<<3, 256, 0, stream>>>(WS, d_out);
}